// Round 9
// baseline (223.189 us; speedup 1.0000x reference)
//
#include <hip/hip_runtime.h>

#define BB 8
#define SS 2048
#define EE 512
#define HD 64
#define CHUNK 256
#define KT 64
#define NCH 8          // max chunks per q-block (SS/CHUNK)
#define PST 72         // P LDS row stride (elems)
#define TST 72         // K/V LDS row stride (elems)
#define XRS 40         // qkv LDS row stride within kb chunk (80B: 16B-aligned reads)
#define XKB 640        // qkv LDS kb-chunk stride (16 rows * XRS)
#define NITEMS 1152    // 8 b * sum_qb (qb/4+1)

typedef __attribute__((ext_vector_type(8))) short bf16x8;
typedef __attribute__((ext_vector_type(4))) float f32x4;

static __device__ __forceinline__ unsigned short f2bf(float f) {
    unsigned u = __builtin_bit_cast(unsigned, f);
    u = (u + 0x7fffu + ((u >> 16) & 1u)) >> 16;  // RNE
    return (unsigned short)u;
}
static __device__ __forceinline__ unsigned short f2bf_trunc(float f) {
    return (unsigned short)(__builtin_bit_cast(unsigned, f) >> 16);
}
static __device__ __forceinline__ float bf2f(unsigned short h) {
    unsigned u = ((unsigned)h) << 16;
    return __builtin_bit_cast(float, u);
}

// pack W (fp32 [E][64] x3) -> bf16 B-fragment layout; Wq pre-scaled by HEAD^-0.5;
// zero the ticket + group counters (device-scope, R5-proven visibility).
__global__ __launch_bounds__(256) void pack_w_kernel(
    const float* __restrict__ Wq, const float* __restrict__ Wk, const float* __restrict__ Wv,
    unsigned short* __restrict__ Wt, int* __restrict__ tickets, int* __restrict__ cnt) {
    if (blockIdx.x == 0) {
        if (threadIdx.x == 0) atomicExch(tickets, 0);
        atomicExch(&cnt[threadIdx.x], 0);  // 256 group counters
    }
    int tid = blockIdx.x * 256 + threadIdx.x;
    if (tid >= 3 * EE * HD) return;
    int w_idx = tid / (EE * HD);
    int rem = tid % (EE * HD);
    int kk = rem / HD, n = rem % HD;
    const float* Wsrc = (w_idx == 0) ? Wq : ((w_idx == 1) ? Wk : Wv);
    float val = Wsrc[kk * HD + n];
    if (w_idx == 0) val *= 0.125f;  // fold scores scale into q
    int kb = kk >> 5, kr = kk & 31, quad = kr >> 3, j = kr & 7;
    int t = n >> 4, c = n & 15;
    int lane = quad * 16 + c;
    Wt[w_idx * (EE * HD) + ((kb * 4 + t) * 64 + lane) * 8 + j] = f2bf(val);
}

// QKV: 1024 blocks x 256 thr, 16 rows/block. x staged kb-major in LDS
// (conflict-lite, 16B-aligned b128 reads). Wave t computes col-tile t of
// ALL THREE matrices: 3 MFMA/kb per wave, perfectly balanced.
__global__ __launch_bounds__(256) void qkv_kernel(
    const float* __restrict__ x,            // [B*S, E] fp32
    const unsigned short* __restrict__ Wt,  // packed bf16, 3*E*64
    unsigned short* __restrict__ q,
    unsigned short* __restrict__ k,
    unsigned short* __restrict__ vT) {
    __shared__ __align__(16) unsigned short Xs[16 * XKB];  // 20.5 KB
    const int tid = threadIdx.x;
    const int lane = tid & 63;
    const int t = tid >> 6;  // wave = output col-tile 0..3
    const int c = lane & 15, quad = lane >> 4;
    const int r0 = blockIdx.x * 16;

    // stage 16 rows x 512 cols fp32 -> bf16 LDS, kb-major
    const float* xt = x + (size_t)r0 * EE;
#pragma unroll
    for (int i = 0; i < 8; ++i) {
        int fi = i * 256 + tid;  // float4 index 0..2047
        int e4 = fi * 4;
        float4 v4 = *(const float4*)(xt + e4);
        int row = e4 >> 9, col = e4 & 511;
        int kb = col >> 5, cc = col & 31;
        ushort4 pk;
        pk.x = f2bf(v4.x); pk.y = f2bf(v4.y); pk.z = f2bf(v4.z); pk.w = f2bf(v4.w);
        *(ushort4*)(&Xs[kb * XKB + row * XRS + cc]) = pk;
    }
    __syncthreads();

    f32x4 acc[3];
    for (int m = 0; m < 3; ++m) acc[m] = (f32x4){0.f, 0.f, 0.f, 0.f};

    const unsigned short* wbase0 = Wt + t * 512 + lane * 8;
#pragma unroll
    for (int kb = 0; kb < EE / 32; ++kb) {
        bf16x8 afrag = *(const bf16x8*)(&Xs[kb * XKB + c * XRS + quad * 8]);
        const unsigned short* wb = wbase0 + kb * 2048;
#pragma unroll
        for (int m = 0; m < 3; ++m) {
            bf16x8 bfrag = *(const bf16x8*)(wb + m * (EE * HD));
            acc[m] = __builtin_amdgcn_mfma_f32_16x16x32_bf16(afrag, bfrag, acc[m], 0, 0, 0);
        }
    }

    const int col = t * 16 + c;
    for (int r = 0; r < 4; ++r) {
        int row = r0 + quad * 4 + r;
        q[(size_t)row * HD + col] = f2bf(acc[0][r]);
        k[(size_t)row * HD + col] = f2bf(acc[1][r]);
    }
    {
        int row = r0 + quad * 4;
        int b_ = row >> 11, sb = row & (SS - 1);
        ushort4 pk;
        pk.x = f2bf(acc[2][0]); pk.y = f2bf(acc[2][1]);
        pk.z = f2bf(acc[2][2]); pk.w = f2bf(acc[2][3]);
        *(ushort4*)(vT + ((size_t)b_ * HD + col) * SS + sb) = pk;
    }
}

// Persistent ticketed split-K attention with fused last-block combine.
// Item = (b, qb, cx): 64 q-rows x one 256-key chunk. Single-chunk items
// (qb<4) write out directly. Multi-chunk: po/pl + fence/atomic; the last
// finisher of each (b,qb) group combines (R5-proven pattern).
__global__ __launch_bounds__(256) void attn_kernel(
    const unsigned short* __restrict__ q,
    const unsigned short* __restrict__ k,
    const unsigned short* __restrict__ vT,
    const int* __restrict__ mask,
    unsigned short* __restrict__ po,   // [B][32][NCH][64 rows][64 d] bf16
    float* __restrict__ pl,            // [B][32][NCH][64 rows] fp32
    int* __restrict__ tickets,
    int* __restrict__ cnt,             // [256] group counters
    float* __restrict__ out) {
    __shared__ __align__(16) unsigned short Ks[2][64 * TST];
    __shared__ __align__(16) unsigned short Vs[2][64 * TST];
    __shared__ __align__(16) unsigned short Ps[4][16 * PST];
    __shared__ int tkt;
    __shared__ int amlast;
    const int tid = threadIdx.x;
    const int lane = tid & 63, wave = tid >> 6;
    const int c = lane & 15, quad = lane >> 4;

    for (;;) {
        __syncthreads();
        if (tid == 0) tkt = atomicAdd(tickets, 1);
        __syncthreads();
        int t = tkt;
        if (t >= NITEMS) break;
        t = NITEMS - 1 - t;                    // big items first
        const int b_ = t / 144;
        int r = t % 144;
        int g = 0;
        while (2 * (g + 1) * (g + 2) <= r) ++g;   // qb-group (nch = g+1)
        int rr = r - 2 * g * (g + 1);
        const int qb = 4 * g + rr / (g + 1);
        const int cx = rr % (g + 1);
        const int kstart = cx * CHUNK;
        const int kend = min(kstart + CHUNK, qb * 64 + 64);
        const int ntiles = (kend - kstart) >> 6;   // 1..4 whole tiles
        const int r0 = qb * 64 + wave * 16;
        const int nch_active = qb / 4 + 1;
        const int gid = b_ * 32 + qb;

        const unsigned short* qb_p = q + (size_t)b_ * SS * HD;
        const unsigned short* kb_p = k + (size_t)b_ * SS * HD;
        const unsigned short* vb = vT + (size_t)b_ * HD * SS;
        const int* mb = mask + b_ * SS;

        bf16x8 aq0 = *(const bf16x8*)(qb_p + (size_t)(r0 + c) * HD + quad * 8);
        bf16x8 aq1 = *(const bf16x8*)(qb_p + (size_t)(r0 + c) * HD + 32 + quad * 8);

        f32x4 o[4];
        for (int tt = 0; tt < 4; ++tt) o[tt] = (f32x4){0.f, 0.f, 0.f, 0.f};
        float l_i[4] = {0.f, 0.f, 0.f, 0.f};

        auto stage = [&](int buf, int k0) {
            const unsigned short* ksrc = kb_p + (size_t)k0 * HD;
            unsigned short* kd = &Ks[buf][0];
            unsigned short* vd = &Vs[buf][0];
#pragma unroll
            for (int rnd = 0; rnd < 2; ++rnd) {
                int e = (rnd * 256 + tid) * 8;
                int krow = e >> 6, kcol = e & 63;
                *(bf16x8*)(kd + krow * TST + kcol) = *(const bf16x8*)(ksrc + e);
                int t8 = rnd * 256 + tid;
                int vr = t8 >> 3, vc = (t8 & 7) * 8;
                *(bf16x8*)(vd + vr * TST + vc) = *(const bf16x8*)(vb + (size_t)vr * SS + k0 + vc);
            }
        };

        stage(0, kstart);
        for (int kt = 0; kt < ntiles; ++kt) {
            __syncthreads();
            const unsigned short* ks = &Ks[kt & 1][0];
            const unsigned short* vs = &Vs[kt & 1][0];
            const int k0 = kstart + kt * KT;
            bf16x8 kf[4][2];
#pragma unroll
            for (int kg = 0; kg < 4; ++kg) {
                kf[kg][0] = *(const bf16x8*)(ks + (kg * 16 + c) * TST + quad * 8);
                kf[kg][1] = *(const bf16x8*)(ks + (kg * 16 + c) * TST + 32 + quad * 8);
            }
            if (kt + 1 < ntiles) stage((kt + 1) & 1, k0 + KT);
            const bool fullc = (k0 + KT <= r0);
            float p[4][4];
#pragma unroll
            for (int kg = 0; kg < 4; ++kg) {
                f32x4 accs = (f32x4){0.f, 0.f, 0.f, 0.f};
                accs = __builtin_amdgcn_mfma_f32_16x16x32_bf16(aq0, kf[kg][0], accs, 0, 0, 0);
                accs = __builtin_amdgcn_mfma_f32_16x16x32_bf16(aq1, kf[kg][1], accs, 0, 0, 0);
                int key = k0 + kg * 16 + c;
                bool mk = (mb[key] != 0);
                for (int rr2 = 0; rr2 < 4; ++rr2) {
                    int row = r0 + quad * 4 + rr2;
                    bool keep = mk && (fullc || key <= row);
                    float e = __expf(fminf(accs[rr2], 80.f));  // scale folded into q
                    float pe = keep ? e : 0.f;
                    p[kg][rr2] = pe;
                    l_i[rr2] += pe;
                }
            }
            unsigned short* pbuf = &Ps[wave][0];
#pragma unroll
            for (int kg = 0; kg < 4; ++kg)
                for (int rr2 = 0; rr2 < 4; ++rr2)
                    pbuf[(quad * 4 + rr2) * PST + kg * 16 + c] = f2bf_trunc(p[kg][rr2]);
            bf16x8 pa0 = *(const bf16x8*)(pbuf + c * PST + quad * 8);
            bf16x8 pa1 = *(const bf16x8*)(pbuf + c * PST + 32 + quad * 8);
#pragma unroll
            for (int tt = 0; tt < 4; ++tt) {
                bf16x8 bv0 = *(const bf16x8*)(vs + (tt * 16 + c) * TST + quad * 8);
                bf16x8 bv1 = *(const bf16x8*)(vs + (tt * 16 + c) * TST + 32 + quad * 8);
                o[tt] = __builtin_amdgcn_mfma_f32_16x16x32_bf16(pa0, bv0, o[tt], 0, 0, 0);
                o[tt] = __builtin_amdgcn_mfma_f32_16x16x32_bf16(pa1, bv1, o[tt], 0, 0, 0);
            }
        }

        for (int rr2 = 0; rr2 < 4; ++rr2) {
            float s = l_i[rr2];
            s += __shfl_xor(s, 1);
            s += __shfl_xor(s, 2);
            s += __shfl_xor(s, 4);
            s += __shfl_xor(s, 8);
            l_i[rr2] = s;
        }

        if (nch_active == 1) {
            // sole chunk for these rows: write final output directly
            for (int rr2 = 0; rr2 < 4; ++rr2) {
                int row = qb * 64 + wave * 16 + quad * 4 + rr2;
                float l = l_i[rr2];
                float inv = (l > 0.f) ? 1.f / l : 0.f;
                for (int tt = 0; tt < 4; ++tt)
                    out[((size_t)b_ * SS + row) * HD + tt * 16 + c] = o[tt][rr2] * inv;
            }
            continue;
        }

        const size_t base = (size_t)gid * NCH + cx;
        for (int rr2 = 0; rr2 < 4; ++rr2) {
            int rl = wave * 16 + quad * 4 + rr2;
            float l = l_i[rr2];
            float inv = (l > 0.f) ? 1.f / l : 0.f;
            for (int tt = 0; tt < 4; ++tt)
                po[base * 4096 + (size_t)rl * 64 + tt * 16 + c] = f2bf(o[tt][rr2] * inv);
            if (c == 0) pl[base * 64 + rl] = l;
        }

        __syncthreads();                 // all waves' stores drained (vmcnt0 before barrier)
        if (tid == 0) {
            __threadfence();             // release this block's po/pl
            int old = atomicAdd(&cnt[gid], 1);
            amlast = (old == nch_active - 1) ? 1 : 0;
        }
        __syncthreads();
        if (!amlast) continue;
        __threadfence();                 // acquire other blocks' po/pl
        const size_t gbase = (size_t)gid * NCH;
        const int q0 = qb * 64;
        for (int i = 0; i < 16; ++i) {
            int e = i * 256 + tid;       // 0..4095
            int rl = e >> 6, d = e & 63;
            float L = 0.f, acc = 0.f;
            for (int cc = 0; cc < nch_active; ++cc) {
                float l = pl[(gbase + cc) * 64 + rl];
                L += l;
                acc += l * bf2f(po[(gbase + cc) * 4096 + (size_t)rl * 64 + d]);
            }
            out[((size_t)b_ * SS + q0 + rl) * HD + d] = (L > 0.f) ? acc / L : 0.f;
        }
    }
}

extern "C" void kernel_launch(void* const* d_in, const int* in_sizes, int n_in,
                              void* d_out, int out_size, void* d_ws, size_t ws_size,
                              hipStream_t stream) {
    const float* x = (const float*)d_in[0];
    const float* Wq = (const float*)d_in[1];
    const float* Wk = (const float*)d_in[2];
    const float* Wv = (const float*)d_in[3];
    const int* mask = (const int*)d_in[4];
    float* out = (float*)d_out;

    // ws: Wt[98304] | q,k,vT[3x1048576] bf16 | po bf16 | pl fp32 | tickets | cnt[256]
    unsigned short* ws = (unsigned short*)d_ws;
    unsigned short* Wt = ws;
    unsigned short* q = Wt + 3 * EE * HD;
    unsigned short* kk = q + (size_t)BB * SS * HD;
    unsigned short* vT = kk + (size_t)BB * SS * HD;
    unsigned short* po = vT + (size_t)BB * SS * HD;
    float* pl = (float*)(po + (size_t)BB * 32 * NCH * 4096);
    int* tickets = (int*)(pl + (size_t)BB * 32 * NCH * 64);
    int* cnt = tickets + 1;

    pack_w_kernel<<<dim3((3 * EE * HD + 255) / 256), dim3(256), 0, stream>>>(Wq, Wk, Wv, Wt, tickets, cnt);
    qkv_kernel<<<dim3(BB * SS / 16), dim3(256), 0, stream>>>(x, Wt, q, kk, vT);
    attn_kernel<<<dim3(768), dim3(256), 0, stream>>>(q, kk, vT, mask, po, pl, tickets, cnt, out);
}

// Round 10
// 125.899 us; speedup vs baseline: 1.7728x; 1.7728x over previous
//
#include <hip/hip_runtime.h>

#define BB 8
#define SS 2048
#define EE 512
#define HD 64
#define CHUNK 256
#define KT 64
#define NCH 8          // max chunks per q-block (SS/CHUNK)
#define PST 72         // P LDS row stride (elems)
#define TST 72         // K/V LDS row stride (elems)
#define XRS 40         // qkv LDS row stride within kb chunk
#define XKB 640        // qkv LDS kb-chunk stride (16 rows * XRS)
#define NITEMS 1152    // 8 b * sum_qb (qb/4+1)

typedef __attribute__((ext_vector_type(8))) short bf16x8;
typedef __attribute__((ext_vector_type(4))) float f32x4;

static __device__ __forceinline__ unsigned short f2bf(float f) {
    unsigned u = __builtin_bit_cast(unsigned, f);
    u = (u + 0x7fffu + ((u >> 16) & 1u)) >> 16;  // RNE
    return (unsigned short)u;
}
static __device__ __forceinline__ unsigned short f2bf_trunc(float f) {
    return (unsigned short)(__builtin_bit_cast(unsigned, f) >> 16);
}
static __device__ __forceinline__ float bf2f(unsigned short h) {
    unsigned u = ((unsigned)h) << 16;
    return __builtin_bit_cast(float, u);
}

// pack W (fp32 [E][64] x3) -> bf16 B-fragment layout; Wq pre-scaled by HEAD^-0.5.
__global__ __launch_bounds__(256) void pack_w_kernel(
    const float* __restrict__ Wq, const float* __restrict__ Wk, const float* __restrict__ Wv,
    unsigned short* __restrict__ Wt, int* __restrict__ tickets) {
    if (blockIdx.x == 0 && threadIdx.x == 0) atomicExch(tickets, 0);
    int tid = blockIdx.x * 256 + threadIdx.x;
    if (tid >= 3 * EE * HD) return;
    int w_idx = tid / (EE * HD);
    int rem = tid % (EE * HD);
    int kk = rem / HD, n = rem % HD;
    const float* Wsrc = (w_idx == 0) ? Wq : ((w_idx == 1) ? Wk : Wv);
    float val = Wsrc[kk * HD + n];
    if (w_idx == 0) val *= 0.125f;  // fold scores scale into q
    int kb = kk >> 5, kr = kk & 31, quad = kr >> 3, j = kr & 7;
    int t = n >> 4, c = n & 15;
    int lane = quad * 16 + c;
    Wt[w_idx * (EE * HD) + ((kb * 4 + t) * 64 + lane) * 8 + j] = f2bf(val);
}

// QKV (R9-proven): 1024 blocks x 256 thr, 16 rows/block. x staged kb-major in
// LDS; wave t computes col-tile t of all three matrices (3 MFMA/kb, balanced).
__global__ __launch_bounds__(256) void qkv_kernel(
    const float* __restrict__ x,            // [B*S, E] fp32
    const unsigned short* __restrict__ Wt,  // packed bf16, 3*E*64
    unsigned short* __restrict__ q,
    unsigned short* __restrict__ k,
    unsigned short* __restrict__ vT) {
    __shared__ __align__(16) unsigned short Xs[16 * XKB];  // 20.5 KB
    const int tid = threadIdx.x;
    const int lane = tid & 63;
    const int t = tid >> 6;  // wave = output col-tile 0..3
    const int c = lane & 15, quad = lane >> 4;
    const int r0 = blockIdx.x * 16;

    const float* xt = x + (size_t)r0 * EE;
#pragma unroll
    for (int i = 0; i < 8; ++i) {
        int fi = i * 256 + tid;
        int e4 = fi * 4;
        float4 v4 = *(const float4*)(xt + e4);
        int row = e4 >> 9, col = e4 & 511;
        int kb = col >> 5, cc = col & 31;
        ushort4 pk;
        pk.x = f2bf(v4.x); pk.y = f2bf(v4.y); pk.z = f2bf(v4.z); pk.w = f2bf(v4.w);
        *(ushort4*)(&Xs[kb * XKB + row * XRS + cc]) = pk;
    }
    __syncthreads();

    f32x4 acc[3];
    for (int m = 0; m < 3; ++m) acc[m] = (f32x4){0.f, 0.f, 0.f, 0.f};

    const unsigned short* wbase0 = Wt + t * 512 + lane * 8;
#pragma unroll
    for (int kb = 0; kb < EE / 32; ++kb) {
        bf16x8 afrag = *(const bf16x8*)(&Xs[kb * XKB + c * XRS + quad * 8]);
        const unsigned short* wb = wbase0 + kb * 2048;
#pragma unroll
        for (int m = 0; m < 3; ++m) {
            bf16x8 bfrag = *(const bf16x8*)(wb + m * (EE * HD));
            acc[m] = __builtin_amdgcn_mfma_f32_16x16x32_bf16(afrag, bfrag, acc[m], 0, 0, 0);
        }
    }

    const int col = t * 16 + c;
    for (int r = 0; r < 4; ++r) {
        int row = r0 + quad * 4 + r;
        q[(size_t)row * HD + col] = f2bf(acc[0][r]);
        k[(size_t)row * HD + col] = f2bf(acc[1][r]);
    }
    {
        int row = r0 + quad * 4;
        int b_ = row >> 11, sb = row & (SS - 1);
        ushort4 pk;
        pk.x = f2bf(acc[2][0]); pk.y = f2bf(acc[2][1]);
        pk.z = f2bf(acc[2][2]); pk.w = f2bf(acc[2][3]);
        *(ushort4*)(vT + ((size_t)b_ * HD + col) * SS + sb) = pk;
    }
}

// Persistent ticketed split-K attention (R7-proven body: NO fences/atomics in
// the loop). Single-chunk items (qb<4) write out directly (fence-free).
__global__ __launch_bounds__(256) void attn_kernel(
    const unsigned short* __restrict__ q,
    const unsigned short* __restrict__ k,
    const unsigned short* __restrict__ vT,
    const int* __restrict__ mask,
    unsigned short* __restrict__ po,   // [B][32][NCH][64 rows][64 d] bf16
    float* __restrict__ pl,            // [B][32][NCH][64 rows] fp32
    int* __restrict__ tickets,
    float* __restrict__ out) {
    __shared__ __align__(16) unsigned short Ks[2][64 * TST];
    __shared__ __align__(16) unsigned short Vs[2][64 * TST];
    __shared__ __align__(16) unsigned short Ps[4][16 * PST];
    __shared__ int tkt;
    const int tid = threadIdx.x;
    const int lane = tid & 63, wave = tid >> 6;
    const int c = lane & 15, quad = lane >> 4;

    for (;;) {
        __syncthreads();
        if (tid == 0) tkt = atomicAdd(tickets, 1);
        __syncthreads();
        int t = tkt;
        if (t >= NITEMS) break;
        t = NITEMS - 1 - t;                    // big items first
        const int b_ = t / 144;
        int r = t % 144;
        int g = 0;
        while (2 * (g + 1) * (g + 2) <= r) ++g;   // qb-group (nch = g+1)
        int rr = r - 2 * g * (g + 1);
        const int qb = 4 * g + rr / (g + 1);
        const int cx = rr % (g + 1);
        const int kstart = cx * CHUNK;
        const int kend = min(kstart + CHUNK, qb * 64 + 64);
        const int ntiles = (kend - kstart) >> 6;   // 1..4 whole tiles
        const int r0 = qb * 64 + wave * 16;
        const int nch_active = qb / 4 + 1;

        const unsigned short* qb_p = q + (size_t)b_ * SS * HD;
        const unsigned short* kb_p = k + (size_t)b_ * SS * HD;
        const unsigned short* vb = vT + (size_t)b_ * HD * SS;
        const int* mb = mask + b_ * SS;

        bf16x8 aq0 = *(const bf16x8*)(qb_p + (size_t)(r0 + c) * HD + quad * 8);
        bf16x8 aq1 = *(const bf16x8*)(qb_p + (size_t)(r0 + c) * HD + 32 + quad * 8);

        f32x4 o[4];
        for (int tt = 0; tt < 4; ++tt) o[tt] = (f32x4){0.f, 0.f, 0.f, 0.f};
        float l_i[4] = {0.f, 0.f, 0.f, 0.f};

        auto stage = [&](int buf, int k0) {
            const unsigned short* ksrc = kb_p + (size_t)k0 * HD;
            unsigned short* kd = &Ks[buf][0];
            unsigned short* vd = &Vs[buf][0];
#pragma unroll
            for (int rnd = 0; rnd < 2; ++rnd) {
                int e = (rnd * 256 + tid) * 8;
                int krow = e >> 6, kcol = e & 63;
                *(bf16x8*)(kd + krow * TST + kcol) = *(const bf16x8*)(ksrc + e);
                int t8 = rnd * 256 + tid;
                int vr = t8 >> 3, vc = (t8 & 7) * 8;
                *(bf16x8*)(vd + vr * TST + vc) = *(const bf16x8*)(vb + (size_t)vr * SS + k0 + vc);
            }
        };

        stage(0, kstart);
        for (int kt = 0; kt < ntiles; ++kt) {
            __syncthreads();
            const unsigned short* ks = &Ks[kt & 1][0];
            const unsigned short* vs = &Vs[kt & 1][0];
            const int k0 = kstart + kt * KT;
            bf16x8 kf[4][2];
#pragma unroll
            for (int kg = 0; kg < 4; ++kg) {
                kf[kg][0] = *(const bf16x8*)(ks + (kg * 16 + c) * TST + quad * 8);
                kf[kg][1] = *(const bf16x8*)(ks + (kg * 16 + c) * TST + 32 + quad * 8);
            }
            if (kt + 1 < ntiles) stage((kt + 1) & 1, k0 + KT);
            const bool fullc = (k0 + KT <= r0);
            float p[4][4];
#pragma unroll
            for (int kg = 0; kg < 4; ++kg) {
                f32x4 accs = (f32x4){0.f, 0.f, 0.f, 0.f};
                accs = __builtin_amdgcn_mfma_f32_16x16x32_bf16(aq0, kf[kg][0], accs, 0, 0, 0);
                accs = __builtin_amdgcn_mfma_f32_16x16x32_bf16(aq1, kf[kg][1], accs, 0, 0, 0);
                int key = k0 + kg * 16 + c;
                bool mk = (mb[key] != 0);
                for (int rr2 = 0; rr2 < 4; ++rr2) {
                    int row = r0 + quad * 4 + rr2;
                    bool keep = mk && (fullc || key <= row);
                    float e = __expf(fminf(accs[rr2], 80.f));  // scale folded into q
                    float pe = keep ? e : 0.f;
                    p[kg][rr2] = pe;
                    l_i[rr2] += pe;
                }
            }
            unsigned short* pbuf = &Ps[wave][0];
#pragma unroll
            for (int kg = 0; kg < 4; ++kg)
                for (int rr2 = 0; rr2 < 4; ++rr2)
                    pbuf[(quad * 4 + rr2) * PST + kg * 16 + c] = f2bf_trunc(p[kg][rr2]);
            bf16x8 pa0 = *(const bf16x8*)(pbuf + c * PST + quad * 8);
            bf16x8 pa1 = *(const bf16x8*)(pbuf + c * PST + 32 + quad * 8);
#pragma unroll
            for (int tt = 0; tt < 4; ++tt) {
                bf16x8 bv0 = *(const bf16x8*)(vs + (tt * 16 + c) * TST + quad * 8);
                bf16x8 bv1 = *(const bf16x8*)(vs + (tt * 16 + c) * TST + 32 + quad * 8);
                o[tt] = __builtin_amdgcn_mfma_f32_16x16x32_bf16(pa0, bv0, o[tt], 0, 0, 0);
                o[tt] = __builtin_amdgcn_mfma_f32_16x16x32_bf16(pa1, bv1, o[tt], 0, 0, 0);
            }
        }

        for (int rr2 = 0; rr2 < 4; ++rr2) {
            float s = l_i[rr2];
            s += __shfl_xor(s, 1);
            s += __shfl_xor(s, 2);
            s += __shfl_xor(s, 4);
            s += __shfl_xor(s, 8);
            l_i[rr2] = s;
        }

        if (nch_active == 1) {
            // sole chunk for these rows: final output, no cross-block consumer
            for (int rr2 = 0; rr2 < 4; ++rr2) {
                int row = qb * 64 + wave * 16 + quad * 4 + rr2;
                float l = l_i[rr2];
                float inv = (l > 0.f) ? 1.f / l : 0.f;
                for (int tt = 0; tt < 4; ++tt)
                    out[((size_t)b_ * SS + row) * HD + tt * 16 + c] = o[tt][rr2] * inv;
            }
            continue;
        }

        const size_t base = (size_t)(b_ * 32 + qb) * NCH + cx;
        for (int rr2 = 0; rr2 < 4; ++rr2) {
            int rl = wave * 16 + quad * 4 + rr2;
            float l = l_i[rr2];
            float inv = (l > 0.f) ? 1.f / l : 0.f;
            for (int tt = 0; tt < 4; ++tt)
                po[base * 4096 + (size_t)rl * 64 + tt * 16 + c] = f2bf(o[tt][rr2] * inv);
            if (c == 0) pl[base * 64 + rl] = l;
        }
    }
}

// Combine rows >= 256 only (qb>=4): out = sum_c l_c * o_c / sum_c l_c.
__global__ __launch_bounds__(256) void combine_kernel(
    const unsigned short* __restrict__ po,
    const float* __restrict__ pl,
    float* __restrict__ out) {
    int t = blockIdx.x * 256 + threadIdx.x;
    if (t >= BB * (SS - 256) * HD) return;
    int d = t & 63;
    int rg = t >> 6;
    int b_ = rg / (SS - 256);
    int row = 256 + rg % (SS - 256);
    int qb = row >> 6, rl = row & 63;
    int nch = row / CHUNK + 1;
    size_t base = (size_t)(b_ * 32 + qb) * NCH;
    float L = 0.f, acc = 0.f;
    for (int c = 0; c < nch; ++c) {
        float l = pl[(base + c) * 64 + rl];
        L += l;
        acc += l * bf2f(po[(base + c) * 4096 + (size_t)rl * 64 + d]);
    }
    out[((size_t)b_ * SS + row) * HD + d] = (L > 0.f) ? acc / L : 0.f;
}

extern "C" void kernel_launch(void* const* d_in, const int* in_sizes, int n_in,
                              void* d_out, int out_size, void* d_ws, size_t ws_size,
                              hipStream_t stream) {
    const float* x = (const float*)d_in[0];
    const float* Wq = (const float*)d_in[1];
    const float* Wk = (const float*)d_in[2];
    const float* Wv = (const float*)d_in[3];
    const int* mask = (const int*)d_in[4];
    float* out = (float*)d_out;

    // ws: Wt[98304] | q,k,vT[3x1048576] bf16 | po bf16 | pl fp32 | tickets
    unsigned short* ws = (unsigned short*)d_ws;
    unsigned short* Wt = ws;
    unsigned short* q = Wt + 3 * EE * HD;
    unsigned short* kk = q + (size_t)BB * SS * HD;
    unsigned short* vT = kk + (size_t)BB * SS * HD;
    unsigned short* po = vT + (size_t)BB * SS * HD;
    float* pl = (float*)(po + (size_t)BB * 32 * NCH * 4096);
    int* tickets = (int*)(pl + (size_t)BB * 32 * NCH * 64);

    pack_w_kernel<<<dim3((3 * EE * HD + 255) / 256), dim3(256), 0, stream>>>(Wq, Wk, Wv, Wt, tickets);
    qkv_kernel<<<dim3(BB * SS / 16), dim3(256), 0, stream>>>(x, Wt, q, kk, vT);
    attn_kernel<<<dim3(768), dim3(256), 0, stream>>>(q, kk, vT, mask, po, pl, tickets, out);
    combine_kernel<<<dim3((BB * (SS - 256) * HD + 255) / 256), dim3(256), 0, stream>>>(po, pl, out);
}

// Round 11
// 124.523 us; speedup vs baseline: 1.7923x; 1.0110x over previous
//
#include <hip/hip_runtime.h>

#define BB 8
#define SS 2048
#define EE 512
#define HD 64
#define CHUNK 256
#define KT 64
#define NCH 8          // max chunks per 64-row q-block (combine layout)
#define PST 72         // P LDS row stride (elems)
#define TST 72         // K/V LDS row stride (elems)
#define XRS 40         // qkv LDS row stride within kb chunk
#define XKB 640        // qkv LDS kb-chunk stride (16 rows * XRS)
#define NITEMS 576     // 8 b * 72 (128-row q-blocks x ceil((Q+1)/2) chunks)

typedef __attribute__((ext_vector_type(8))) short bf16x8;
typedef __attribute__((ext_vector_type(4))) float f32x4;

static __device__ __forceinline__ unsigned short f2bf(float f) {
    unsigned u = __builtin_bit_cast(unsigned, f);
    u = (u + 0x7fffu + ((u >> 16) & 1u)) >> 16;  // RNE
    return (unsigned short)u;
}
static __device__ __forceinline__ unsigned short f2bf_trunc(float f) {
    return (unsigned short)(__builtin_bit_cast(unsigned, f) >> 16);
}
static __device__ __forceinline__ float bf2f(unsigned short h) {
    unsigned u = ((unsigned)h) << 16;
    return __builtin_bit_cast(float, u);
}

// pack W (fp32 [E][64] x3) -> bf16 B-fragment layout; Wq pre-scaled by HEAD^-0.5.
__global__ __launch_bounds__(256) void pack_w_kernel(
    const float* __restrict__ Wq, const float* __restrict__ Wk, const float* __restrict__ Wv,
    unsigned short* __restrict__ Wt, int* __restrict__ tickets) {
    if (blockIdx.x == 0 && threadIdx.x == 0) atomicExch(tickets, 0);
    int tid = blockIdx.x * 256 + threadIdx.x;
    if (tid >= 3 * EE * HD) return;
    int w_idx = tid / (EE * HD);
    int rem = tid % (EE * HD);
    int kk = rem / HD, n = rem % HD;
    const float* Wsrc = (w_idx == 0) ? Wq : ((w_idx == 1) ? Wk : Wv);
    float val = Wsrc[kk * HD + n];
    if (w_idx == 0) val *= 0.125f;  // fold scores scale into q
    int kb = kk >> 5, kr = kk & 31, quad = kr >> 3, j = kr & 7;
    int t = n >> 4, c = n & 15;
    int lane = quad * 16 + c;
    Wt[w_idx * (EE * HD) + ((kb * 4 + t) * 64 + lane) * 8 + j] = f2bf(val);
}

// QKV (proven): 1024 blocks x 256 thr, 16 rows/block; x staged kb-major in LDS;
// wave t computes col-tile t of all three matrices (3 MFMA/kb, balanced).
__global__ __launch_bounds__(256) void qkv_kernel(
    const float* __restrict__ x,            // [B*S, E] fp32
    const unsigned short* __restrict__ Wt,  // packed bf16, 3*E*64
    unsigned short* __restrict__ q,
    unsigned short* __restrict__ k,
    unsigned short* __restrict__ vT) {
    __shared__ __align__(16) unsigned short Xs[16 * XKB];  // 20.5 KB
    const int tid = threadIdx.x;
    const int lane = tid & 63;
    const int t = tid >> 6;  // wave = output col-tile 0..3
    const int c = lane & 15, quad = lane >> 4;
    const int r0 = blockIdx.x * 16;

    const float* xt = x + (size_t)r0 * EE;
#pragma unroll
    for (int i = 0; i < 8; ++i) {
        int fi = i * 256 + tid;
        int e4 = fi * 4;
        float4 v4 = *(const float4*)(xt + e4);
        int row = e4 >> 9, col = e4 & 511;
        int kb = col >> 5, cc = col & 31;
        ushort4 pk;
        pk.x = f2bf(v4.x); pk.y = f2bf(v4.y); pk.z = f2bf(v4.z); pk.w = f2bf(v4.w);
        *(ushort4*)(&Xs[kb * XKB + row * XRS + cc]) = pk;
    }
    __syncthreads();

    f32x4 acc[3];
    for (int m = 0; m < 3; ++m) acc[m] = (f32x4){0.f, 0.f, 0.f, 0.f};

    const unsigned short* wbase0 = Wt + t * 512 + lane * 8;
#pragma unroll
    for (int kb = 0; kb < EE / 32; ++kb) {
        bf16x8 afrag = *(const bf16x8*)(&Xs[kb * XKB + c * XRS + quad * 8]);
        const unsigned short* wb = wbase0 + kb * 2048;
#pragma unroll
        for (int m = 0; m < 3; ++m) {
            bf16x8 bfrag = *(const bf16x8*)(wb + m * (EE * HD));
            acc[m] = __builtin_amdgcn_mfma_f32_16x16x32_bf16(afrag, bfrag, acc[m], 0, 0, 0);
        }
    }

    const int col = t * 16 + c;
    for (int r = 0; r < 4; ++r) {
        int row = r0 + quad * 4 + r;
        q[(size_t)row * HD + col] = f2bf(acc[0][r]);
        k[(size_t)row * HD + col] = f2bf(acc[1][r]);
    }
    {
        int row = r0 + quad * 4;
        int b_ = row >> 11, sb = row & (SS - 1);
        ushort4 pk;
        pk.x = f2bf(acc[2][0]); pk.y = f2bf(acc[2][1]);
        pk.z = f2bf(acc[2][2]); pk.w = f2bf(acc[2][3]);
        *(ushort4*)(vT + ((size_t)b_ * HD + col) * SS + sb) = pk;
    }
}

// Ticketed split-K attention, 128-row q-items: item = (b, Q, cx) covering
// 128 q-rows x one 256-key chunk; each wave owns 32 rows (2 row-tiles).
// 576 items on 768 blocks -> one item per block, <=4 serial tiles.
// 2x MFMA per staged tile vs R10. No fences/atomics beyond the ticket.
__global__ __launch_bounds__(256, 3) void attn_kernel(
    const unsigned short* __restrict__ q,
    const unsigned short* __restrict__ k,
    const unsigned short* __restrict__ vT,
    const int* __restrict__ mask,
    unsigned short* __restrict__ po,   // [B][32 qb][NCH][64 rows][64 d] bf16
    float* __restrict__ pl,            // [B][32 qb][NCH][64 rows] fp32
    int* __restrict__ tickets,
    float* __restrict__ out) {
    __shared__ __align__(16) unsigned short Ks[2][64 * TST];
    __shared__ __align__(16) unsigned short Vs[2][64 * TST];
    __shared__ __align__(16) unsigned short Ps[4][16 * PST];
    __shared__ int tkt;
    const int tid = threadIdx.x;
    const int lane = tid & 63, wave = tid >> 6;
    const int c = lane & 15, quad = lane >> 4;

    for (;;) {
        __syncthreads();
        if (tid == 0) tkt = atomicAdd(tickets, 1);
        __syncthreads();
        int t = tkt;
        if (t >= NITEMS) break;
        t = NITEMS - 1 - t;                    // big items first
        const int b_ = t / 72;
        int r = t % 72;
        int g = 0;
        while ((g + 1) * (g + 2) <= r) ++g;    // group: Q in {2g,2g+1}, nch=g+1
        int rr = r - g * (g + 1);
        const int Q = 2 * g + rr / (g + 1);
        const int cx = rr % (g + 1);
        const int kstart = cx * CHUNK;
        const int kend = min(kstart + CHUNK, Q * 128 + 128);
        const int ntiles = (kend - kstart) >> 6;   // 1..4 whole tiles
        const int nch_active = Q / 2 + 1;
        const int r0 = Q * 128 + wave * 32;        // this wave's first row

        const unsigned short* qb_p = q + (size_t)b_ * SS * HD;
        const unsigned short* kb_p = k + (size_t)b_ * SS * HD;
        const unsigned short* vb = vT + (size_t)b_ * HD * SS;
        const int* mb = mask + b_ * SS;

        bf16x8 aq[2][2];
#pragma unroll
        for (int rt = 0; rt < 2; ++rt) {
            const unsigned short* qrow = qb_p + (size_t)(r0 + rt * 16 + c) * HD + quad * 8;
            aq[rt][0] = *(const bf16x8*)(qrow);
            aq[rt][1] = *(const bf16x8*)(qrow + 32);
        }

        f32x4 o[2][4];
        float l_i[2][4];
#pragma unroll
        for (int rt = 0; rt < 2; ++rt)
            for (int tt = 0; tt < 4; ++tt) {
                o[rt][tt] = (f32x4){0.f, 0.f, 0.f, 0.f};
                l_i[rt][tt] = 0.f;
            }

        auto stage = [&](int buf, int k0) {
            const unsigned short* ksrc = kb_p + (size_t)k0 * HD;
            unsigned short* kd = &Ks[buf][0];
            unsigned short* vd = &Vs[buf][0];
#pragma unroll
            for (int rnd = 0; rnd < 2; ++rnd) {
                int e = (rnd * 256 + tid) * 8;
                int krow = e >> 6, kcol = e & 63;
                *(bf16x8*)(kd + krow * TST + kcol) = *(const bf16x8*)(ksrc + e);
                int t8 = rnd * 256 + tid;
                int vr = t8 >> 3, vc = (t8 & 7) * 8;
                *(bf16x8*)(vd + vr * TST + vc) = *(const bf16x8*)(vb + (size_t)vr * SS + k0 + vc);
            }
        };

        stage(0, kstart);
        for (int kt = 0; kt < ntiles; ++kt) {
            __syncthreads();
            const unsigned short* ks = &Ks[kt & 1][0];
            const unsigned short* vs = &Vs[kt & 1][0];
            const int k0 = kstart + kt * KT;
            bf16x8 kf[4][2];
#pragma unroll
            for (int kg = 0; kg < 4; ++kg) {
                kf[kg][0] = *(const bf16x8*)(ks + (kg * 16 + c) * TST + quad * 8);
                kf[kg][1] = *(const bf16x8*)(ks + (kg * 16 + c) * TST + 32 + quad * 8);
            }
            if (kt + 1 < ntiles) stage((kt + 1) & 1, k0 + KT);
#pragma unroll
            for (int rt = 0; rt < 2; ++rt) {
                const int rbase = r0 + rt * 16;
                const bool fullc = (k0 + KT <= rbase);
                float p[4][4];
#pragma unroll
                for (int kg = 0; kg < 4; ++kg) {
                    f32x4 accs = (f32x4){0.f, 0.f, 0.f, 0.f};
                    accs = __builtin_amdgcn_mfma_f32_16x16x32_bf16(aq[rt][0], kf[kg][0], accs, 0, 0, 0);
                    accs = __builtin_amdgcn_mfma_f32_16x16x32_bf16(aq[rt][1], kf[kg][1], accs, 0, 0, 0);
                    int key = k0 + kg * 16 + c;
                    bool mk = (mb[key] != 0);
                    for (int rr2 = 0; rr2 < 4; ++rr2) {
                        int row = rbase + quad * 4 + rr2;
                        bool keep = mk && (fullc || key <= row);
                        float e = __expf(fminf(accs[rr2], 80.f));  // scale folded into q
                        float pe = keep ? e : 0.f;
                        p[kg][rr2] = pe;
                        l_i[rt][rr2] += pe;
                    }
                }
                unsigned short* pbuf = &Ps[wave][0];
#pragma unroll
                for (int kg = 0; kg < 4; ++kg)
                    for (int rr2 = 0; rr2 < 4; ++rr2)
                        pbuf[(quad * 4 + rr2) * PST + kg * 16 + c] = f2bf_trunc(p[kg][rr2]);
                bf16x8 pa0 = *(const bf16x8*)(pbuf + c * PST + quad * 8);
                bf16x8 pa1 = *(const bf16x8*)(pbuf + c * PST + 32 + quad * 8);
#pragma unroll
                for (int tt = 0; tt < 4; ++tt) {
                    bf16x8 bv0 = *(const bf16x8*)(vs + (tt * 16 + c) * TST + quad * 8);
                    bf16x8 bv1 = *(const bf16x8*)(vs + (tt * 16 + c) * TST + 32 + quad * 8);
                    o[rt][tt] = __builtin_amdgcn_mfma_f32_16x16x32_bf16(pa0, bv0, o[rt][tt], 0, 0, 0);
                    o[rt][tt] = __builtin_amdgcn_mfma_f32_16x16x32_bf16(pa1, bv1, o[rt][tt], 0, 0, 0);
                }
            }
        }

#pragma unroll
        for (int rt = 0; rt < 2; ++rt)
            for (int rr2 = 0; rr2 < 4; ++rr2) {
                float s = l_i[rt][rr2];
                s += __shfl_xor(s, 1);
                s += __shfl_xor(s, 2);
                s += __shfl_xor(s, 4);
                s += __shfl_xor(s, 8);
                l_i[rt][rr2] = s;
            }

        if (nch_active == 1) {
            // rows < 256: sole chunk, final output directly
#pragma unroll
            for (int rt = 0; rt < 2; ++rt)
                for (int rr2 = 0; rr2 < 4; ++rr2) {
                    int row = r0 + rt * 16 + quad * 4 + rr2;
                    float l = l_i[rt][rr2];
                    float inv = (l > 0.f) ? 1.f / l : 0.f;
                    for (int tt = 0; tt < 4; ++tt)
                        out[((size_t)b_ * SS + row) * HD + tt * 16 + c] = o[rt][tt][rr2] * inv;
                }
            continue;
        }

#pragma unroll
        for (int rt = 0; rt < 2; ++rt)
            for (int rr2 = 0; rr2 < 4; ++rr2) {
                int row_abs = r0 + rt * 16 + quad * 4 + rr2;
                int qb_i = row_abs >> 6, rl = row_abs & 63;
                size_t base = (size_t)(b_ * 32 + qb_i) * NCH + cx;
                float l = l_i[rt][rr2];
                float inv = (l > 0.f) ? 1.f / l : 0.f;
                for (int tt = 0; tt < 4; ++tt)
                    po[base * 4096 + (size_t)rl * 64 + tt * 16 + c] = f2bf(o[rt][tt][rr2] * inv);
                if (c == 0) pl[base * 64 + rl] = l;
            }
    }
}

// Combine rows >= 256 only: out = sum_c l_c * o_c / sum_c l_c.
__global__ __launch_bounds__(256) void combine_kernel(
    const unsigned short* __restrict__ po,
    const float* __restrict__ pl,
    float* __restrict__ out) {
    int t = blockIdx.x * 256 + threadIdx.x;
    if (t >= BB * (SS - 256) * HD) return;
    int d = t & 63;
    int rg = t >> 6;
    int b_ = rg / (SS - 256);
    int row = 256 + rg % (SS - 256);
    int qb = row >> 6, rl = row & 63;
    int nch = row / CHUNK + 1;
    size_t base = (size_t)(b_ * 32 + qb) * NCH;
    float L = 0.f, acc = 0.f;
    for (int c = 0; c < nch; ++c) {
        float l = pl[(base + c) * 64 + rl];
        L += l;
        acc += l * bf2f(po[(base + c) * 4096 + (size_t)rl * 64 + d]);
    }
    out[((size_t)b_ * SS + row) * HD + d] = (L > 0.f) ? acc / L : 0.f;
}

extern "C" void kernel_launch(void* const* d_in, const int* in_sizes, int n_in,
                              void* d_out, int out_size, void* d_ws, size_t ws_size,
                              hipStream_t stream) {
    const float* x = (const float*)d_in[0];
    const float* Wq = (const float*)d_in[1];
    const float* Wk = (const float*)d_in[2];
    const float* Wv = (const float*)d_in[3];
    const int* mask = (const int*)d_in[4];
    float* out = (float*)d_out;

    // ws: Wt[98304] | q,k,vT[3x1048576] bf16 | po bf16 | pl fp32 | tickets
    unsigned short* ws = (unsigned short*)d_ws;
    unsigned short* Wt = ws;
    unsigned short* q = Wt + 3 * EE * HD;
    unsigned short* kk = q + (size_t)BB * SS * HD;
    unsigned short* vT = kk + (size_t)BB * SS * HD;
    unsigned short* po = vT + (size_t)BB * SS * HD;
    float* pl = (float*)(po + (size_t)BB * 32 * NCH * 4096);
    int* tickets = (int*)(pl + (size_t)BB * 32 * NCH * 64);

    pack_w_kernel<<<dim3((3 * EE * HD + 255) / 256), dim3(256), 0, stream>>>(Wq, Wk, Wv, Wt, tickets);
    qkv_kernel<<<dim3(BB * SS / 16), dim3(256), 0, stream>>>(x, Wt, q, kk, vT);
    attn_kernel<<<dim3(768), dim3(256), 0, stream>>>(q, kk, vT, mask, po, pl, tickets, out);
    combine_kernel<<<dim3((BB * (SS - 256) * HD + 255) / 256), dim3(256), 0, stream>>>(po, pl, out);
}

// Round 12
// 113.716 us; speedup vs baseline: 1.9627x; 1.0950x over previous
//
#include <hip/hip_runtime.h>

#define BB 8
#define SS 2048
#define EE 512
#define HD 64
#define CHUNK 256
#define KT 64
#define NCH 8          // max chunks per 64-row q-block (combine layout)
#define PST 72         // P LDS row stride (elems)
#define TST 72         // K/V LDS row stride (elems)
#define XRS 40         // qkv LDS row stride within kb chunk
#define XKB 1280       // qkv LDS kb-chunk stride (32 rows * XRS)
#define NITEMS 576     // 8 b * 72 (128-row q-blocks x ceil((Q+1)/2) chunks)

typedef __attribute__((ext_vector_type(8))) short bf16x8;
typedef __attribute__((ext_vector_type(4))) float f32x4;

static __device__ __forceinline__ unsigned short f2bf(float f) {
    unsigned u = __builtin_bit_cast(unsigned, f);
    u = (u + 0x7fffu + ((u >> 16) & 1u)) >> 16;  // RNE
    return (unsigned short)u;
}
static __device__ __forceinline__ unsigned short f2bf_trunc(float f) {
    return (unsigned short)(__builtin_bit_cast(unsigned, f) >> 16);
}
static __device__ __forceinline__ float bf2f(unsigned short h) {
    unsigned u = ((unsigned)h) << 16;
    return __builtin_bit_cast(float, u);
}

// pack W (fp32 [E][64] x3) -> bf16 B-fragment layout; Wq pre-scaled by HEAD^-0.5.
__global__ __launch_bounds__(256) void pack_w_kernel(
    const float* __restrict__ Wq, const float* __restrict__ Wk, const float* __restrict__ Wv,
    unsigned short* __restrict__ Wt) {
    int tid = blockIdx.x * 256 + threadIdx.x;
    if (tid >= 3 * EE * HD) return;
    int w_idx = tid / (EE * HD);
    int rem = tid % (EE * HD);
    int kk = rem / HD, n = rem % HD;
    const float* Wsrc = (w_idx == 0) ? Wq : ((w_idx == 1) ? Wk : Wv);
    float val = Wsrc[kk * HD + n];
    if (w_idx == 0) val *= 0.125f;  // fold scores scale into q
    int kb = kk >> 5, kr = kk & 31, quad = kr >> 3, j = kr & 7;
    int t = n >> 4, c = n & 15;
    int lane = quad * 16 + c;
    Wt[w_idx * (EE * HD) + ((kb * 4 + t) * 64 + lane) * 8 + j] = f2bf(val);
}

// QKV v3: 512 blocks x 256 thr, 32 rows/block. x staged kb-major in LDS (40 KB).
// Wave t = col-tile t of all three matrices; per kb: 3 bfrags loaded ONCE,
// used for both row-tiles (2 afrag + 3 bfrag + 6 MFMA) -> halved Wt traffic.
__global__ __launch_bounds__(256) void qkv_kernel(
    const float* __restrict__ x,            // [B*S, E] fp32
    const unsigned short* __restrict__ Wt,  // packed bf16, 3*E*64
    unsigned short* __restrict__ q,
    unsigned short* __restrict__ k,
    unsigned short* __restrict__ vT) {
    __shared__ __align__(16) unsigned short Xs[16 * XKB];  // 40 KB
    const int tid = threadIdx.x;
    const int lane = tid & 63;
    const int t = tid >> 6;  // wave = output col-tile 0..3
    const int c = lane & 15, quad = lane >> 4;
    const int r0 = blockIdx.x * 32;

    // stage 32 rows x 512 cols fp32 -> bf16 LDS, kb-major
    const float* xt = x + (size_t)r0 * EE;
#pragma unroll
    for (int i = 0; i < 16; ++i) {
        int fi = i * 256 + tid;  // float4 index 0..4095
        int e4 = fi * 4;
        float4 v4 = *(const float4*)(xt + e4);
        int row = e4 >> 9, col = e4 & 511;
        int kb = col >> 5, cc = col & 31;
        ushort4 pk;
        pk.x = f2bf(v4.x); pk.y = f2bf(v4.y); pk.z = f2bf(v4.z); pk.w = f2bf(v4.w);
        *(ushort4*)(&Xs[kb * XKB + row * XRS + cc]) = pk;
    }
    __syncthreads();

    f32x4 acc[2][3];
#pragma unroll
    for (int rt = 0; rt < 2; ++rt)
        for (int m = 0; m < 3; ++m) acc[rt][m] = (f32x4){0.f, 0.f, 0.f, 0.f};

    const unsigned short* wbase0 = Wt + t * 512 + lane * 8;
#pragma unroll
    for (int kb = 0; kb < EE / 32; ++kb) {
        const unsigned short* wb = wbase0 + kb * 2048;
        bf16x8 bfrag[3];
#pragma unroll
        for (int m = 0; m < 3; ++m) bfrag[m] = *(const bf16x8*)(wb + m * (EE * HD));
#pragma unroll
        for (int rt = 0; rt < 2; ++rt) {
            bf16x8 afrag = *(const bf16x8*)(&Xs[kb * XKB + (rt * 16 + c) * XRS + quad * 8]);
#pragma unroll
            for (int m = 0; m < 3; ++m)
                acc[rt][m] = __builtin_amdgcn_mfma_f32_16x16x32_bf16(afrag, bfrag[m], acc[rt][m], 0, 0, 0);
        }
    }

    const int col = t * 16 + c;
#pragma unroll
    for (int rt = 0; rt < 2; ++rt) {
        const int rb = r0 + rt * 16;
        for (int r = 0; r < 4; ++r) {
            int row = rb + quad * 4 + r;
            q[(size_t)row * HD + col] = f2bf(acc[rt][0][r]);
            k[(size_t)row * HD + col] = f2bf(acc[rt][1][r]);
        }
        int row = rb + quad * 4;
        int b_ = row >> 11, sb = row & (SS - 1);
        ushort4 pk;
        pk.x = f2bf(acc[rt][2][0]); pk.y = f2bf(acc[rt][2][1]);
        pk.z = f2bf(acc[rt][2][2]); pk.w = f2bf(acc[rt][2][3]);
        *(ushort4*)(vT + ((size_t)b_ * HD + col) * SS + sb) = pk;
    }
}

// Split-K attention, 128-row q-items, direct blockIdx mapping (one item per
// block, no ticket). Item = (b, Q, cx): 128 q-rows x one 256-key chunk; each
// wave owns 32 rows (2 row-tiles). Body identical to R11.
__global__ __launch_bounds__(256, 3) void attn_kernel(
    const unsigned short* __restrict__ q,
    const unsigned short* __restrict__ k,
    const unsigned short* __restrict__ vT,
    const int* __restrict__ mask,
    unsigned short* __restrict__ po,   // [B][32 qb][NCH][64 rows][64 d] bf16
    float* __restrict__ pl,            // [B][32 qb][NCH][64 rows] fp32
    float* __restrict__ out) {
    __shared__ __align__(16) unsigned short Ks[2][64 * TST];
    __shared__ __align__(16) unsigned short Vs[2][64 * TST];
    __shared__ __align__(16) unsigned short Ps[4][16 * PST];
    const int tid = threadIdx.x;
    const int lane = tid & 63, wave = tid >> 6;
    const int c = lane & 15, quad = lane >> 4;

    int t = NITEMS - 1 - blockIdx.x;       // big items first (low blockIdx)
    const int b_ = t / 72;
    int r = t % 72;
    int g = 0;
    while ((g + 1) * (g + 2) <= r) ++g;    // group: Q in {2g,2g+1}, nch=g+1
    int rr = r - g * (g + 1);
    const int Q = 2 * g + rr / (g + 1);
    const int cx = rr % (g + 1);
    const int kstart = cx * CHUNK;
    const int kend = min(kstart + CHUNK, Q * 128 + 128);
    const int ntiles = (kend - kstart) >> 6;   // 1..4 whole tiles
    const int nch_active = Q / 2 + 1;
    const int r0 = Q * 128 + wave * 32;        // this wave's first row

    const unsigned short* qb_p = q + (size_t)b_ * SS * HD;
    const unsigned short* kb_p = k + (size_t)b_ * SS * HD;
    const unsigned short* vb = vT + (size_t)b_ * HD * SS;
    const int* mb = mask + b_ * SS;

    bf16x8 aq[2][2];
#pragma unroll
    for (int rt = 0; rt < 2; ++rt) {
        const unsigned short* qrow = qb_p + (size_t)(r0 + rt * 16 + c) * HD + quad * 8;
        aq[rt][0] = *(const bf16x8*)(qrow);
        aq[rt][1] = *(const bf16x8*)(qrow + 32);
    }

    f32x4 o[2][4];
    float l_i[2][4];
#pragma unroll
    for (int rt = 0; rt < 2; ++rt)
        for (int tt = 0; tt < 4; ++tt) {
            o[rt][tt] = (f32x4){0.f, 0.f, 0.f, 0.f};
            l_i[rt][tt] = 0.f;
        }

    auto stage = [&](int buf, int k0) {
        const unsigned short* ksrc = kb_p + (size_t)k0 * HD;
        unsigned short* kd = &Ks[buf][0];
        unsigned short* vd = &Vs[buf][0];
#pragma unroll
        for (int rnd = 0; rnd < 2; ++rnd) {
            int e = (rnd * 256 + tid) * 8;
            int krow = e >> 6, kcol = e & 63;
            *(bf16x8*)(kd + krow * TST + kcol) = *(const bf16x8*)(ksrc + e);
            int t8 = rnd * 256 + tid;
            int vr = t8 >> 3, vc = (t8 & 7) * 8;
            *(bf16x8*)(vd + vr * TST + vc) = *(const bf16x8*)(vb + (size_t)vr * SS + k0 + vc);
        }
    };

    stage(0, kstart);
    for (int kt = 0; kt < ntiles; ++kt) {
        __syncthreads();
        const unsigned short* ks = &Ks[kt & 1][0];
        const unsigned short* vs = &Vs[kt & 1][0];
        const int k0 = kstart + kt * KT;
        bf16x8 kf[4][2];
#pragma unroll
        for (int kg = 0; kg < 4; ++kg) {
            kf[kg][0] = *(const bf16x8*)(ks + (kg * 16 + c) * TST + quad * 8);
            kf[kg][1] = *(const bf16x8*)(ks + (kg * 16 + c) * TST + 32 + quad * 8);
        }
        if (kt + 1 < ntiles) stage((kt + 1) & 1, k0 + KT);
#pragma unroll
        for (int rt = 0; rt < 2; ++rt) {
            const int rbase = r0 + rt * 16;
            const bool fullc = (k0 + KT <= rbase);
            float p[4][4];
#pragma unroll
            for (int kg = 0; kg < 4; ++kg) {
                f32x4 accs = (f32x4){0.f, 0.f, 0.f, 0.f};
                accs = __builtin_amdgcn_mfma_f32_16x16x32_bf16(aq[rt][0], kf[kg][0], accs, 0, 0, 0);
                accs = __builtin_amdgcn_mfma_f32_16x16x32_bf16(aq[rt][1], kf[kg][1], accs, 0, 0, 0);
                int key = k0 + kg * 16 + c;
                bool mk = (mb[key] != 0);
                for (int rr2 = 0; rr2 < 4; ++rr2) {
                    int row = rbase + quad * 4 + rr2;
                    bool keep = mk && (fullc || key <= row);
                    float e = __expf(fminf(accs[rr2], 80.f));  // scale folded into q
                    float pe = keep ? e : 0.f;
                    p[kg][rr2] = pe;
                    l_i[rt][rr2] += pe;
                }
            }
            unsigned short* pbuf = &Ps[wave][0];
#pragma unroll
            for (int kg = 0; kg < 4; ++kg)
                for (int rr2 = 0; rr2 < 4; ++rr2)
                    pbuf[(quad * 4 + rr2) * PST + kg * 16 + c] = f2bf_trunc(p[kg][rr2]);
            bf16x8 pa0 = *(const bf16x8*)(pbuf + c * PST + quad * 8);
            bf16x8 pa1 = *(const bf16x8*)(pbuf + c * PST + 32 + quad * 8);
#pragma unroll
            for (int tt = 0; tt < 4; ++tt) {
                bf16x8 bv0 = *(const bf16x8*)(vs + (tt * 16 + c) * TST + quad * 8);
                bf16x8 bv1 = *(const bf16x8*)(vs + (tt * 16 + c) * TST + 32 + quad * 8);
                o[rt][tt] = __builtin_amdgcn_mfma_f32_16x16x32_bf16(pa0, bv0, o[rt][tt], 0, 0, 0);
                o[rt][tt] = __builtin_amdgcn_mfma_f32_16x16x32_bf16(pa1, bv1, o[rt][tt], 0, 0, 0);
            }
        }
    }

#pragma unroll
    for (int rt = 0; rt < 2; ++rt)
        for (int rr2 = 0; rr2 < 4; ++rr2) {
            float s = l_i[rt][rr2];
            s += __shfl_xor(s, 1);
            s += __shfl_xor(s, 2);
            s += __shfl_xor(s, 4);
            s += __shfl_xor(s, 8);
            l_i[rt][rr2] = s;
        }

    if (nch_active == 1) {
        // rows < 256: sole chunk, final output directly
#pragma unroll
        for (int rt = 0; rt < 2; ++rt)
            for (int rr2 = 0; rr2 < 4; ++rr2) {
                int row = r0 + rt * 16 + quad * 4 + rr2;
                float l = l_i[rt][rr2];
                float inv = (l > 0.f) ? 1.f / l : 0.f;
                for (int tt = 0; tt < 4; ++tt)
                    out[((size_t)b_ * SS + row) * HD + tt * 16 + c] = o[rt][tt][rr2] * inv;
            }
        return;
    }

#pragma unroll
    for (int rt = 0; rt < 2; ++rt)
        for (int rr2 = 0; rr2 < 4; ++rr2) {
            int row_abs = r0 + rt * 16 + quad * 4 + rr2;
            int qb_i = row_abs >> 6, rl = row_abs & 63;
            size_t base = (size_t)(b_ * 32 + qb_i) * NCH + cx;
            float l = l_i[rt][rr2];
            float inv = (l > 0.f) ? 1.f / l : 0.f;
            for (int tt = 0; tt < 4; ++tt)
                po[base * 4096 + (size_t)rl * 64 + tt * 16 + c] = f2bf(o[rt][tt][rr2] * inv);
            if (c == 0) pl[base * 64 + rl] = l;
        }
}

// Combine rows >= 256 only: out = sum_c l_c * o_c / sum_c l_c.
__global__ __launch_bounds__(256) void combine_kernel(
    const unsigned short* __restrict__ po,
    const float* __restrict__ pl,
    float* __restrict__ out) {
    int t = blockIdx.x * 256 + threadIdx.x;
    if (t >= BB * (SS - 256) * HD) return;
    int d = t & 63;
    int rg = t >> 6;
    int b_ = rg / (SS - 256);
    int row = 256 + rg % (SS - 256);
    int qb = row >> 6, rl = row & 63;
    int nch = row / CHUNK + 1;
    size_t base = (size_t)(b_ * 32 + qb) * NCH;
    float L = 0.f, acc = 0.f;
    for (int c = 0; c < nch; ++c) {
        float l = pl[(base + c) * 64 + rl];
        L += l;
        acc += l * bf2f(po[(base + c) * 4096 + (size_t)rl * 64 + d]);
    }
    out[((size_t)b_ * SS + row) * HD + d] = (L > 0.f) ? acc / L : 0.f;
}

extern "C" void kernel_launch(void* const* d_in, const int* in_sizes, int n_in,
                              void* d_out, int out_size, void* d_ws, size_t ws_size,
                              hipStream_t stream) {
    const float* x = (const float*)d_in[0];
    const float* Wq = (const float*)d_in[1];
    const float* Wk = (const float*)d_in[2];
    const float* Wv = (const float*)d_in[3];
    const int* mask = (const int*)d_in[4];
    float* out = (float*)d_out;

    // ws: Wt[98304] | q,k,vT[3x1048576] bf16 | po bf16 | pl fp32
    unsigned short* ws = (unsigned short*)d_ws;
    unsigned short* Wt = ws;
    unsigned short* q = Wt + 3 * EE * HD;
    unsigned short* kk = q + (size_t)BB * SS * HD;
    unsigned short* vT = kk + (size_t)BB * SS * HD;
    unsigned short* po = vT + (size_t)BB * SS * HD;
    float* pl = (float*)(po + (size_t)BB * 32 * NCH * 4096);

    pack_w_kernel<<<dim3((3 * EE * HD + 255) / 256), dim3(256), 0, stream>>>(Wq, Wk, Wv, Wt);
    qkv_kernel<<<dim3(BB * SS / 32), dim3(256), 0, stream>>>(x, Wt, q, kk, vT);
    attn_kernel<<<dim3(NITEMS), dim3(256), 0, stream>>>(q, kk, vT, mask, po, pl, out);
    combine_kernel<<<dim3((BB * (SS - 256) * HD + 255) / 256), dim3(256), 0, stream>>>(po, pl, out);
}